// Round 3
// baseline (674.803 us; speedup 1.0000x reference)
//
#include <hip/hip_runtime.h>
#include <stdint.h>

// Problem constants (fixed by setup_inputs). All tensors fp32.
#define IMG_H   512
#define IMG_W   512
#define PADDING 12
#define EMB     768
#define FLAT    256
#define MTILE   64
#define LDA     264      // 256 + 8 ushort pad -> ds_read_b128 max 2-way conflict (free)
#define NTILES  2048     // 131072 patches / 64
#define TILE_WS 36864    // bytes per tile in ws: 64 patches * 528B = 33792, rounded to 9*4096
#define WB_BYTES 393216  // 768*256*2

typedef __attribute__((ext_vector_type(8))) short short8;
typedef __attribute__((ext_vector_type(4))) float floatx4;

__device__ __forceinline__ ushort f2bf(float f) {
  union { float f; uint32_t i; } c; c.f = f;
  uint32_t u = c.i + 0x7FFFu + ((c.i >> 16) & 1u);   // round-to-nearest-even
  return (ushort)(u >> 16);
}

// ---- pre-pass: W fp32 [768][256] -> bf16 in d_ws (once per launch) ----
__global__ __launch_bounds__(256) void convert_w_kernel(
    const float* __restrict__ W, ushort* __restrict__ Wb) {
  int i = (blockIdx.x * 256 + threadIdx.x) * 8;   // 24576 threads * 8 = 196608 exact
  float4 a = *(const float4*)(W + i);
  float4 b = *(const float4*)(W + i + 4);
  short8 t;
  t[0] = (short)f2bf(a.x); t[1] = (short)f2bf(a.y);
  t[2] = (short)f2bf(a.z); t[3] = (short)f2bf(a.w);
  t[4] = (short)f2bf(b.x); t[5] = (short)f2bf(b.y);
  t[6] = (short)f2bf(b.z); t[7] = (short)f2bf(b.w);
  *(short8*)(Wb + i) = t;
}

// ---- split path, kernel A: gather patches -> ws (bf16, padded tile layout) ----
// Branchless clamped scalar loads (round-0 style, proven best MLP). Low VGPR
// -> 8 waves/SIMD: the latency-bound gather finally gets its TLP.
__global__ __launch_bounds__(256) void gather_kernel(
    const float* __restrict__ img,   // [32][512][512] fp32
    const int*   __restrict__ kp,    // [32][4096][2] int32 (x,y)
    const int*   __restrict__ sh,    // [32][4096][2] int32
    ushort*      __restrict__ wsA)   // tile t, patch p at t*TILE_WS + p*528 bytes
{
  int gid = blockIdx.x * 256 + threadIdx.x;   // one 8-elem segment per thread
  int m = gid >> 5;                // patch 0..131071
  int q = gid & 31;                // segment within patch
  int2 k2 = *(const int2*)(kp + 2 * (size_t)m);
  int2 s2 = *(const int2*)(sh + 2 * (size_t)m);
  int r  = q >> 1;                 // patch row 0..15
  int c0 = (q & 1) << 3;           // col 0 or 8
  int y  = k2.y + s2.y + r  - PADDING;
  int xb = k2.x + s2.x + c0 - PADDING;
  int b  = m >> 12;                // batch (T=4096)
  bool rowok = (y >= 0) & (y < IMG_H);
  int  yc = min(max(y, 0), IMG_H - 1);
  const float* rp = img + (size_t)b * (size_t)(IMG_H * IMG_W) + (size_t)yc * IMG_W;
  uint32_t pk[4];
  #pragma unroll
  for (int j = 0; j < 4; j++) {
    int x0 = xb + 2 * j, x1 = x0 + 1;
    bool ok0 = rowok & (x0 >= 0) & (x0 < IMG_W);
    bool ok1 = rowok & (x1 >= 0) & (x1 < IMG_W);
    int x0c = min(max(x0, 0), IMG_W - 1);
    int x1c = min(max(x1, 0), IMG_W - 1);
    float f0 = rp[x0c], f1 = rp[x1c];
    ushort v0 = ok0 ? f2bf(f0) : (ushort)0;
    ushort v1 = ok1 ? f2bf(f1) : (ushort)0;
    pk[j] = (uint32_t)v0 | ((uint32_t)v1 << 16);
  }
  int t = m >> 6, p = m & 63;
  uint32_t* dst = (uint32_t*)((char*)wsA + (size_t)t * TILE_WS + p * 528 + q * 16);
  dst[0] = pk[0]; dst[1] = pk[1]; dst[2] = pk[2]; dst[3] = pk[3];
}

// ---- split path, kernel B: GEMM from ws tiles (global_load_lds staging) ----
__global__ __launch_bounds__(256) void gemm_kernel(
    const ushort* __restrict__ wsA,
    const ushort* __restrict__ Wb,    // [768][256] bf16
    const float*  __restrict__ bl,    // [768] fp32
    float*        __restrict__ out)   // [32][4096][768] fp32
{
  __shared__ __align__(16) ushort A[TILE_WS / 2];   // 36864 B, linear image of ws tile

  const int tid  = threadIdx.x;
  const int lane = tid & 63;
  const int w    = tid >> 6;
  const int t    = blockIdx.x;
  const int m0   = t * MTILE;

  // stage tile: 9 * 4KB coalesced async copies; linear dest == padded layout
  const char* gsrc = (const char*)wsA + (size_t)t * TILE_WS + w * 1024 + lane * 16;
  char*       ldst = (char*)A + w * 1024;           // wave-uniform base (+lane*16 in HW)
  #pragma unroll
  for (int it = 0; it < 9; it++) {
    __builtin_amdgcn_global_load_lds(
        (const __attribute__((address_space(1))) uint32_t*)(gsrc + it * 4096),
        (__attribute__((address_space(3))) uint32_t*)(ldst + it * 4096),
        16, 0, 0);
  }
  asm volatile("s_waitcnt vmcnt(0)");
  __syncthreads();

  const int lm = lane & 15;     // A: m / B: e / C/D: col(n)
  const int kq = lane >> 4;     // k-quad

  for (int ec = 0; ec < 3; ec++) {
    const int e0 = ec * 256 + w * 64;
    floatx4 acc[4][4];
    #pragma unroll
    for (int mi = 0; mi < 4; mi++)
      #pragma unroll
      for (int ni = 0; ni < 4; ni++)
        acc[mi][ni] = (floatx4){0.f, 0.f, 0.f, 0.f};

    #pragma unroll
    for (int kk = 0; kk < 8; kk++) {          // K = 8 * 32
      short8 af[4];
      #pragma unroll
      for (int mi = 0; mi < 4; mi++)
        af[mi] = *(const short8*)&A[(mi * 16 + lm) * LDA + kk * 32 + kq * 8];
      #pragma unroll
      for (int ni = 0; ni < 4; ni++) {
        short8 bfr = *(const short8*)&Wb[(size_t)(e0 + ni * 16 + lm) * FLAT + kk * 32 + kq * 8];
        #pragma unroll
        for (int mi = 0; mi < 4; mi++)
          acc[mi][ni] = __builtin_amdgcn_mfma_f32_16x16x32_bf16(af[mi], bfr, acc[mi][ni], 0, 0, 0);
      }
    }

    // C/D layout (verified m89/m91): n(col)=lane&15, m(row)=(lane>>4)*4+reg
    #pragma unroll
    for (int ni = 0; ni < 4; ni++) {
      int e = e0 + ni * 16 + lm;
      float bias = bl[e];
      #pragma unroll
      for (int mi = 0; mi < 4; mi++) {
        int mbase = m0 + mi * 16 + kq * 4;
        #pragma unroll
        for (int rg = 0; rg < 4; rg++)
          out[(size_t)(mbase + rg) * EMB + e] = acc[mi][ni][rg] + bias;
      }
    }
  }
}

// ---- fallback: fused round-0 kernel (used only if ws too small) ----
__global__ __launch_bounds__(256) void patch_embed_fused(
    const float*  __restrict__ img, const int* __restrict__ kp,
    const int*    __restrict__ sh,  const ushort* __restrict__ Wb,
    const float*  __restrict__ bl,  float* __restrict__ out)
{
  __shared__ __align__(16) ushort A[MTILE * LDA];
  __shared__ int sx[MTILE], sy[MTILE];
  const int tid = threadIdx.x;
  const int m0  = blockIdx.x * MTILE;
  if (tid < MTILE) {
    int m = m0 + tid;
    sx[tid] = kp[2 * m]     + sh[2 * m];
    sy[tid] = kp[2 * m + 1] + sh[2 * m + 1];
  }
  __syncthreads();
  #pragma unroll
  for (int it = 0; it < 8; it++) {
    int s  = it * 256 + tid;
    int p  = s >> 5, q = s & 31;
    int r  = q >> 1, c0 = (q & 1) << 3;
    int y  = sy[p] + r  - PADDING;
    int xb = sx[p] + c0 - PADDING;
    int b  = (m0 + p) >> 12;
    bool rowok = (y >= 0) & (y < IMG_H);
    int  yc = min(max(y, 0), IMG_H - 1);
    const float* rp = img + (size_t)b * (size_t)(IMG_H * IMG_W) + (size_t)yc * IMG_W;
    uint32_t pk[4];
    #pragma unroll
    for (int j = 0; j < 4; j++) {
      int x0 = xb + 2 * j, x1 = x0 + 1;
      bool ok0 = rowok & (x0 >= 0) & (x0 < IMG_W);
      bool ok1 = rowok & (x1 >= 0) & (x1 < IMG_W);
      int x0c = min(max(x0, 0), IMG_W - 1);
      int x1c = min(max(x1, 0), IMG_W - 1);
      float f0 = rp[x0c], f1 = rp[x1c];
      ushort v0 = ok0 ? f2bf(f0) : (ushort)0;
      ushort v1 = ok1 ? f2bf(f1) : (ushort)0;
      pk[j] = (uint32_t)v0 | ((uint32_t)v1 << 16);
    }
    uint32_t* dst = (uint32_t*)&A[p * LDA + q * 8];
    dst[0] = pk[0]; dst[1] = pk[1]; dst[2] = pk[2]; dst[3] = pk[3];
  }
  __syncthreads();
  const int lane = tid & 63, w = tid >> 6;
  const int lm = lane & 15, kq = lane >> 4;
  for (int ec = 0; ec < 3; ec++) {
    const int e0 = ec * 256 + w * 64;
    floatx4 acc[4][4];
    #pragma unroll
    for (int mi = 0; mi < 4; mi++)
      #pragma unroll
      for (int ni = 0; ni < 4; ni++)
        acc[mi][ni] = (floatx4){0.f, 0.f, 0.f, 0.f};
    #pragma unroll
    for (int kk = 0; kk < 8; kk++) {
      short8 af[4];
      #pragma unroll
      for (int mi = 0; mi < 4; mi++)
        af[mi] = *(const short8*)&A[(mi * 16 + lm) * LDA + kk * 32 + kq * 8];
      #pragma unroll
      for (int ni = 0; ni < 4; ni++) {
        short8 bfr = *(const short8*)&Wb[(size_t)(e0 + ni * 16 + lm) * FLAT + kk * 32 + kq * 8];
        #pragma unroll
        for (int mi = 0; mi < 4; mi++)
          acc[mi][ni] = __builtin_amdgcn_mfma_f32_16x16x32_bf16(af[mi], bfr, acc[mi][ni], 0, 0, 0);
      }
    }
    #pragma unroll
    for (int ni = 0; ni < 4; ni++) {
      int e = e0 + ni * 16 + lm;
      float bias = bl[e];
      #pragma unroll
      for (int mi = 0; mi < 4; mi++) {
        int mbase = m0 + mi * 16 + kq * 4;
        #pragma unroll
        for (int rg = 0; rg < 4; rg++)
          out[(size_t)(mbase + rg) * EMB + e] = acc[mi][ni][rg] + bias;
      }
    }
  }
}

extern "C" void kernel_launch(void* const* d_in, const int* in_sizes, int n_in,
                              void* d_out, int out_size, void* d_ws, size_t ws_size,
                              hipStream_t stream) {
  const float* img = (const float*)d_in[0];
  const int*   kp  = (const int*)d_in[1];
  const int*   sh  = (const int*)d_in[2];
  const float* Wl  = (const float*)d_in[3];
  const float* bl  = (const float*)d_in[4];
  float*       out = (float*)d_out;
  ushort*      Wb  = (ushort*)d_ws;                      // [768][256] bf16
  ushort*      wsA = (ushort*)((char*)d_ws + WB_BYTES);  // padded patch tiles

  hipLaunchKernelGGL(convert_w_kernel, dim3(96), dim3(256), 0, stream, Wl, Wb);

  const size_t need = (size_t)WB_BYTES + (size_t)NTILES * TILE_WS;  // ~75.9 MB
  if (ws_size >= need) {
    hipLaunchKernelGGL(gather_kernel, dim3(131072 * 32 / 256), dim3(256), 0, stream,
                       img, kp, sh, wsA);
    hipLaunchKernelGGL(gemm_kernel, dim3(NTILES), dim3(256), 0, stream,
                       wsA, Wb, bl, out);
  } else {
    hipLaunchKernelGGL(patch_embed_fused, dim3(NTILES), dim3(256), 0, stream,
                       img, kp, sh, Wb, bl, out);
  }
}

// Round 4
// 616.775 us; speedup vs baseline: 1.0941x; 1.0941x over previous
//
#include <hip/hip_runtime.h>
#include <stdint.h>

// Problem constants (fixed by setup_inputs). All tensors fp32.
#define IMG_H   512
#define IMG_W   512
#define PADDING 12
#define EMB     768
#define FLAT    256
#define MTILE   64
#define HALF    32
#define LDA     264      // 256 + 8 ushort pad -> ds_read_b128 max 2-way conflict (free)
#define WB_BYTES 393216  // 768*256*2

typedef __attribute__((ext_vector_type(8))) short short8;
typedef __attribute__((ext_vector_type(4))) float floatx4;

__device__ __forceinline__ ushort f2bf(float f) {
  union { float f; uint32_t i; } c; c.f = f;
  uint32_t u = c.i + 0x7FFFu + ((c.i >> 16) & 1u);   // round-to-nearest-even
  return (ushort)(u >> 16);
}

// ---- pre-pass: W fp32 [768][256] -> bf16 in d_ws (once per launch) ----
__global__ __launch_bounds__(256) void convert_w_kernel(
    const float* __restrict__ W, ushort* __restrict__ Wb) {
  int i = (blockIdx.x * 256 + threadIdx.x) * 8;   // 24576 threads * 8 = 196608 exact
  float4 a = *(const float4*)(W + i);
  float4 b = *(const float4*)(W + i + 4);
  short8 t;
  t[0] = (short)f2bf(a.x); t[1] = (short)f2bf(a.y);
  t[2] = (short)f2bf(a.z); t[3] = (short)f2bf(a.w);
  t[4] = (short)f2bf(b.x); t[5] = (short)f2bf(b.y);
  t[6] = (short)f2bf(b.z); t[7] = (short)f2bf(b.w);
  *(short8*)(Wb + i) = t;
}

// Fused, half-tile double-buffered pipeline. NO launch_bounds min-waves arg
// (round 1: (256,4) snapped allocator to 64 VGPR and spilled the accumulator).
__global__ __launch_bounds__(256) void patch_embed_kernel(
    const float*  __restrict__ img,   // [32][512][512] fp32
    const int*    __restrict__ kp,    // [32][4096][2] int32 (x,y)
    const int*    __restrict__ sh,    // [32][4096][2] int32
    const ushort* __restrict__ Wb,    // [768][256] bf16 (pre-converted, ws)
    const float*  __restrict__ bl,    // [768] fp32
    float*        __restrict__ out)   // [32][4096][768] fp32
{
  __shared__ __align__(16) ushort A0[HALF * LDA];
  __shared__ __align__(16) ushort A1[HALF * LDA];
  __shared__ int sx[MTILE], sy[MTILE];

  const int tid = threadIdx.x;
  const int m0  = blockIdx.x * MTILE;
  // batch is block-uniform: 64 | 4096
  const float* ib = img + (size_t)(m0 >> 12) * (size_t)(IMG_H * IMG_W);

  if (tid < MTILE) {
    int m = m0 + tid;
    sx[tid] = kp[2 * m]     + sh[2 * m];       // x start (padded coords)
    sy[tid] = kp[2 * m + 1] + sh[2 * m + 1];   // y start
  }
  __syncthreads();

  // ---- gather half0 (patches 0..31) -> LDS A0, branchless clamped loads ----
  #pragma unroll
  for (int it = 0; it < 4; it++) {
    int s  = it * 256 + tid;        // 0..1023
    int p  = s >> 5;                // patch 0..31
    int q  = s & 31;
    int r  = q >> 1;
    int c0 = (q & 1) << 3;
    int y  = sy[p] + r  - PADDING;
    int xb = sx[p] + c0 - PADDING;
    bool rowok = (y >= 0) & (y < IMG_H);
    int  yc = min(max(y, 0), IMG_H - 1);
    const float* rp = ib + (size_t)yc * IMG_W;
    uint32_t pk[4];
    #pragma unroll
    for (int j = 0; j < 4; j++) {
      int x0 = xb + 2 * j, x1 = x0 + 1;
      bool ok0 = rowok & (x0 >= 0) & (x0 < IMG_W);
      bool ok1 = rowok & (x1 >= 0) & (x1 < IMG_W);
      int x0c = min(max(x0, 0), IMG_W - 1);
      int x1c = min(max(x1, 0), IMG_W - 1);
      float f0 = rp[x0c], f1 = rp[x1c];
      ushort v0 = ok0 ? f2bf(f0) : (ushort)0;
      ushort v1 = ok1 ? f2bf(f1) : (ushort)0;
      pk[j] = (uint32_t)v0 | ((uint32_t)v1 << 16);
    }
    uint32_t* dst = (uint32_t*)&A0[p * LDA + q * 8];   // 16B-aligned
    dst[0] = pk[0]; dst[1] = pk[1]; dst[2] = pk[2]; dst[3] = pk[3];
  }

  // ---- issue half1 loads (patches 32..63) into registers NOW ----
  // They stay in flight across the barrier and GEMM(A0); pack happens after.
  float g0[4][4], g1[4][4];        // fully unrolled -> registers (rule #20 ok)
  uint32_t okm[4];
  #pragma unroll
  for (int it = 0; it < 4; it++) {
    int s  = it * 256 + tid;
    int p  = 32 + (s >> 5);
    int q  = s & 31;
    int r  = q >> 1;
    int c0 = (q & 1) << 3;
    int y  = sy[p] + r  - PADDING;
    int xb = sx[p] + c0 - PADDING;
    bool rowok = (y >= 0) & (y < IMG_H);
    int  yc = min(max(y, 0), IMG_H - 1);
    const float* rp = ib + (size_t)yc * IMG_W;
    uint32_t mbits = 0;
    #pragma unroll
    for (int j = 0; j < 4; j++) {
      int x0 = xb + 2 * j, x1 = x0 + 1;
      bool ok0 = rowok & (x0 >= 0) & (x0 < IMG_W);
      bool ok1 = rowok & (x1 >= 0) & (x1 < IMG_W);
      int x0c = min(max(x0, 0), IMG_W - 1);
      int x1c = min(max(x1, 0), IMG_W - 1);
      g0[it][j] = rp[x0c];
      g1[it][j] = rp[x1c];
      mbits |= (ok0 ? 1u : 0u) << (2 * j);
      mbits |= (ok1 ? 1u : 0u) << (2 * j + 1);
    }
    okm[it] = mbits;
  }

  __syncthreads();   // A0 visible to all waves

  const int lane = tid & 63;
  const int w    = tid >> 6;      // wave 0..3 -> E offset
  const int lm   = lane & 15;     // A: m / B: e / C/D: col(n)
  const int kq   = lane >> 4;     // k-quad

  // GEMM over one 32-row half; C/D layout (m89/m91): col=lane&15, row=(lane>>4)*4+reg
  auto gemm_half = [&](const ushort* Ab, int mbase) {
    for (int ec = 0; ec < 3; ec++) {
      const int e0 = ec * 256 + w * 64;
      floatx4 acc[2][4];
      #pragma unroll
      for (int mi = 0; mi < 2; mi++)
        #pragma unroll
        for (int ni = 0; ni < 4; ni++)
          acc[mi][ni] = (floatx4){0.f, 0.f, 0.f, 0.f};

      #pragma unroll
      for (int kk = 0; kk < 8; kk++) {          // K = 8 * 32
        short8 af[2];
        #pragma unroll
        for (int mi = 0; mi < 2; mi++)
          af[mi] = *(const short8*)&Ab[(mi * 16 + lm) * LDA + kk * 32 + kq * 8];
        #pragma unroll
        for (int ni = 0; ni < 4; ni++) {
          short8 bfr = *(const short8*)&Wb[(size_t)(e0 + ni * 16 + lm) * FLAT + kk * 32 + kq * 8];
          #pragma unroll
          for (int mi = 0; mi < 2; mi++)
            acc[mi][ni] = __builtin_amdgcn_mfma_f32_16x16x32_bf16(af[mi], bfr, acc[mi][ni], 0, 0, 0);
        }
      }

      #pragma unroll
      for (int ni = 0; ni < 4; ni++) {
        int e = e0 + ni * 16 + lm;
        float bias = bl[e];
        #pragma unroll
        for (int mi = 0; mi < 2; mi++) {
          int mb = mbase + mi * 16 + kq * 4;
          #pragma unroll
          for (int rg = 0; rg < 4; rg++)
            out[(size_t)(mb + rg) * EMB + e] = acc[mi][ni][rg] + bias;
        }
      }
    }
  };

  // ---- GEMM half0 (half1 loads in flight underneath) ----
  gemm_half(A0, m0);

  // ---- pack half1 (waits land here) + write A1 ----
  #pragma unroll
  for (int it = 0; it < 4; it++) {
    int s = it * 256 + tid;
    int p = s >> 5;
    int q = s & 31;
    uint32_t pk[4];
    #pragma unroll
    for (int j = 0; j < 4; j++) {
      ushort v0 = ((okm[it] >> (2 * j))     & 1u) ? f2bf(g0[it][j]) : (ushort)0;
      ushort v1 = ((okm[it] >> (2 * j + 1)) & 1u) ? f2bf(g1[it][j]) : (ushort)0;
      pk[j] = (uint32_t)v0 | ((uint32_t)v1 << 16);
    }
    uint32_t* dst = (uint32_t*)&A1[p * LDA + q * 8];
    dst[0] = pk[0]; dst[1] = pk[1]; dst[2] = pk[2]; dst[3] = pk[3];
  }
  __syncthreads();

  // ---- GEMM half1 ----
  gemm_half(A1, m0 + HALF);
}

extern "C" void kernel_launch(void* const* d_in, const int* in_sizes, int n_in,
                              void* d_out, int out_size, void* d_ws, size_t ws_size,
                              hipStream_t stream) {
  const float* img = (const float*)d_in[0];
  const int*   kp  = (const int*)d_in[1];
  const int*   sh  = (const int*)d_in[2];
  const float* Wl  = (const float*)d_in[3];
  const float* bl  = (const float*)d_in[4];
  float*       out = (float*)d_out;
  ushort*      Wb  = (ushort*)d_ws;           // 768*256*2 = 393216 B scratch

  // pre-convert W to bf16 (196608 elems / 8 per thread / 256 = 96 blocks)
  hipLaunchKernelGGL(convert_w_kernel, dim3(96), dim3(256), 0, stream, Wl, Wb);

  const int Mtotal = 32 * 4096;               // 131072 patches
  hipLaunchKernelGGL(patch_embed_kernel, dim3(Mtotal / MTILE), dim3(256), 0, stream,
                     img, kp, sh, Wb, bl, out);
}

// Round 5
// 573.852 us; speedup vs baseline: 1.1759x; 1.0748x over previous
//
#include <hip/hip_runtime.h>
#include <stdint.h>

// Problem constants (fixed by setup_inputs). All tensors fp32.
#define IMG_H   512
#define IMG_W   512
#define PADDING 12
#define EMB     768
#define FLAT    256
#define MTILE   64
#define LDA     264   // 256 + 8 ushort pad -> ds_read_b128 max 2-way conflict (free)
#define NXCD    8

typedef __attribute__((ext_vector_type(8))) short short8;
typedef __attribute__((ext_vector_type(4))) float floatx4;

__device__ __forceinline__ ushort f2bf(float f) {
  union { float f; uint32_t i; } c; c.f = f;
  uint32_t u = c.i + 0x7FFFu + ((c.i >> 16) & 1u);   // round-to-nearest-even
  return (ushort)(u >> 16);
}

// ---- pre-pass: W fp32 [768][256] -> bf16 in d_ws (once per launch) ----
__global__ __launch_bounds__(256) void convert_w_kernel(
    const float* __restrict__ W, ushort* __restrict__ Wb) {
  int i = (blockIdx.x * 256 + threadIdx.x) * 8;   // 24576 threads * 8 = 196608 exact
  float4 a = *(const float4*)(W + i);
  float4 b = *(const float4*)(W + i + 4);
  short8 t;
  t[0] = (short)f2bf(a.x); t[1] = (short)f2bf(a.y);
  t[2] = (short)f2bf(a.z); t[3] = (short)f2bf(a.w);
  t[4] = (short)f2bf(b.x); t[5] = (short)f2bf(b.y);
  t[6] = (short)f2bf(b.z); t[7] = (short)f2bf(b.w);
  *(short8*)(Wb + i) = t;
}

// Round-0 structure (best measured: 253us) + ONE change: XCD-aware block
// swizzle. Default dispatch round-robins consecutive blocks (same image)
// across the 8 XCD L2s -> each XCD's resident blocks span ~12 images, 12MB
// working set thrashes the 4MB L2 (FETCH_SIZE ~113MB = full gather volume
// missing L2). Swizzle gives each XCD a contiguous 256-tile chunk = 4 whole
// images -> ~1.5MB resident working set, gather becomes L2-hit.
// NO launch_bounds min-waves arg (round 1: allocator snapped to 64 VGPR and
// spilled the accumulator). NO branchy gather fast path (round 2: divergent
// if kills load pipelining, 253->278us). NO half-tile pipeline (round 4:
// occupancy 2x, dur unchanged -> not TLP-bound).
__global__ __launch_bounds__(256) void patch_embed_kernel(
    const float*  __restrict__ img,   // [32][512][512] fp32
    const int*    __restrict__ kp,    // [32][4096][2] int32 (x,y)
    const int*    __restrict__ sh,    // [32][4096][2] int32
    const ushort* __restrict__ Wb,    // [768][256] bf16 (pre-converted, ws)
    const float*  __restrict__ bl,    // [768] fp32
    float*        __restrict__ out)   // [32][4096][768] fp32
{
  __shared__ __align__(16) ushort A[MTILE * LDA];
  __shared__ int sx[MTILE], sy[MTILE];

  const int tid = threadIdx.x;
  // ---- XCD-aware swizzle (bijective: 2048 % 8 == 0) ----
  // XCD x (= blockIdx.x % 8 under round-robin dispatch) processes the
  // contiguous tile chunk [x*256, (x+1)*256) = images [4x, 4x+4).
  const int nwg   = (int)gridDim.x;          // 2048
  const int cpx   = nwg / NXCD;              // 256
  const int tno   = (blockIdx.x % NXCD) * cpx + blockIdx.x / NXCD;
  const int m0    = tno * MTILE;

  // ---- stage patch start coords ----
  if (tid < MTILE) {
    int m = m0 + tid;
    sx[tid] = kp[2 * m]     + sh[2 * m];       // x start (padded coords)
    sy[tid] = kp[2 * m + 1] + sh[2 * m + 1];   // y start
  }
  __syncthreads();

  // ---- gather 64 patches x 256 elems into LDS as bf16 (zero outside) ----
  // Branchless clamped addresses (always in-bounds) + select-to-zero.
  #pragma unroll
  for (int it = 0; it < 8; it++) {
    int s  = it * 256 + tid;        // 0..2047
    int p  = s >> 5;                // patch within tile
    int q  = s & 31;                // 8-elem segment within patch
    int r  = q >> 1;                // patch row 0..15
    int c0 = (q & 1) << 3;          // col 0 or 8
    int y  = sy[p] + r  - PADDING;  // original-image row (may be <0 or >=512)
    int xb = sx[p] + c0 - PADDING;
    int b  = (m0 + p) >> 12;        // batch (T=4096)
    bool rowok = (y >= 0) & (y < IMG_H);
    int  yc = min(max(y, 0), IMG_H - 1);
    size_t base = ((size_t)b * (size_t)(IMG_H * IMG_W)) + (size_t)yc * IMG_W;
    uint32_t pk[4];
    #pragma unroll
    for (int j = 0; j < 4; j++) {
      int x0 = xb + 2 * j, x1 = x0 + 1;
      bool ok0 = rowok & (x0 >= 0) & (x0 < IMG_W);
      bool ok1 = rowok & (x1 >= 0) & (x1 < IMG_W);
      int x0c = min(max(x0, 0), IMG_W - 1);
      int x1c = min(max(x1, 0), IMG_W - 1);
      float f0 = img[base + x0c], f1 = img[base + x1c];
      ushort v0 = ok0 ? f2bf(f0) : (ushort)0;
      ushort v1 = ok1 ? f2bf(f1) : (ushort)0;
      pk[j] = (uint32_t)v0 | ((uint32_t)v1 << 16);
    }
    uint32_t* dst = (uint32_t*)&A[p * LDA + q * 8];   // 16B-aligned
    dst[0] = pk[0]; dst[1] = pk[1]; dst[2] = pk[2]; dst[3] = pk[3];
  }
  __syncthreads();

  // ---- MFMA GEMM: each wave does 64M x 64E, loop 3 E-chunks ----
  const int lane = tid & 63;
  const int w    = tid >> 6;      // wave 0..3 -> E offset
  const int lm   = lane & 15;     // A: m / B: e / C/D: col(n)
  const int kq   = lane >> 4;     // k-quad

  for (int ec = 0; ec < 3; ec++) {
    const int e0 = ec * 256 + w * 64;
    floatx4 acc[4][4];
    #pragma unroll
    for (int mi = 0; mi < 4; mi++)
      #pragma unroll
      for (int ni = 0; ni < 4; ni++)
        acc[mi][ni] = (floatx4){0.f, 0.f, 0.f, 0.f};

    #pragma unroll
    for (int kk = 0; kk < 8; kk++) {          // K = 8 * 32
      short8 af[4], bfr[4];
      #pragma unroll
      for (int mi = 0; mi < 4; mi++)
        af[mi] = *(const short8*)&A[(mi * 16 + lm) * LDA + kk * 32 + kq * 8];
      #pragma unroll
      for (int ni = 0; ni < 4; ni++)
        bfr[ni] = *(const short8*)&Wb[(size_t)(e0 + ni * 16 + lm) * FLAT + kk * 32 + kq * 8];
      #pragma unroll
      for (int mi = 0; mi < 4; mi++)
        #pragma unroll
        for (int ni = 0; ni < 4; ni++)
          acc[mi][ni] = __builtin_amdgcn_mfma_f32_16x16x32_bf16(af[mi], bfr[ni], acc[mi][ni], 0, 0, 0);
    }

    // ---- epilogue: bias + fp32 store ----
    // C/D layout (verified m89/m91): n(col)=lane&15, m(row)=(lane>>4)*4+reg
    #pragma unroll
    for (int ni = 0; ni < 4; ni++) {
      int e = e0 + ni * 16 + lm;
      float bias = bl[e];
      #pragma unroll
      for (int mi = 0; mi < 4; mi++) {
        int mbase = m0 + mi * 16 + kq * 4;
        #pragma unroll
        for (int rg = 0; rg < 4; rg++)
          out[(size_t)(mbase + rg) * EMB + e] = acc[mi][ni][rg] + bias;
      }
    }
  }
}

extern "C" void kernel_launch(void* const* d_in, const int* in_sizes, int n_in,
                              void* d_out, int out_size, void* d_ws, size_t ws_size,
                              hipStream_t stream) {
  const float* img = (const float*)d_in[0];
  const int*   kp  = (const int*)d_in[1];
  const int*   sh  = (const int*)d_in[2];
  const float* Wl  = (const float*)d_in[3];
  const float* bl  = (const float*)d_in[4];
  float*       out = (float*)d_out;
  ushort*      Wb  = (ushort*)d_ws;           // 768*256*2 = 393216 B scratch

  // pre-convert W to bf16 (196608 elems / 8 per thread / 256 = 96 blocks)
  hipLaunchKernelGGL(convert_w_kernel, dim3(96), dim3(256), 0, stream, Wl, Wb);

  const int Mtotal = 32 * 4096;               // 131072 patches
  hipLaunchKernelGGL(patch_embed_kernel, dim3(Mtotal / MTILE), dim3(256), 0, stream,
                     img, kp, sh, Wb, bl, out);
}